// Round 3
// baseline (1907.894 us; speedup 1.0000x reference)
//
#include <hip/hip_runtime.h>

// LightGCN via bucketed unweighted propagation.
// Identity: z = dis (.) x  =>  z_k[c] = (1/deg_c) * sum_{r->c} z_{k-1}[r],
//           x_k = sqrt(deg) (.) z_k,  out = 0.25*(emb + sdeg (.)(z1+z2+z3)).
// Edges binned by target into buckets of 128 nodes; record = r | (c&127)<<20.
// One workgroup per bucket: 128x64 fp32 LDS accumulator, ds_add_f32 scatter.

#define BKT_SHIFT 7
#define BKT_NODES 128
#define BKT_CAP   2048   // mean 1600 edges/bucket, +11 sigma headroom

__global__ void k_init(int* __restrict__ bcursor, int nbkt) {
  int i = blockIdx.x * blockDim.x + threadIdx.x;
  if (i < nbkt) bcursor[i] = i * BKT_CAP;
}

__global__ void k_bin(const int* __restrict__ row, const int* __restrict__ col,
                      int* __restrict__ bcursor, int* __restrict__ tmp, int E) {
  int e = blockIdx.x * blockDim.x + threadIdx.x;
  if (e >= E) return;
  int r = row[e], c = col[e];
  int b = c >> BKT_SHIFT;
  int p = atomicAdd(&bcursor[b], 1);
  tmp[p] = r | ((c & (BKT_NODES - 1)) << 20);
}

// per-bucket: LDS degree histogram -> invdeg, sdeg, and z0 = emb * dis
__global__ __launch_bounds__(256)
void k_hist(const int* __restrict__ bcursor, const int* __restrict__ tmp,
            const float* __restrict__ emb, float* __restrict__ z0,
            float* __restrict__ invdeg, float* __restrict__ sdeg, int n) {
  __shared__ int hist[BKT_NODES];
  __shared__ float sdis[BKT_NODES];
  int b = blockIdx.x;
  int base = b * BKT_CAP;
  int cnt = bcursor[b] - base;
  for (int i = threadIdx.x; i < BKT_NODES; i += blockDim.x) hist[i] = 0;
  __syncthreads();
  for (int q = threadIdx.x; q < cnt; q += blockDim.x)
    atomicAdd(&hist[tmp[base + q] >> 20], 1);
  __syncthreads();
  int node0 = b << BKT_SHIFT;
  for (int i = threadIdx.x; i < BKT_NODES; i += blockDim.x) {
    int node = node0 + i;
    if (node < n) {
      int d = hist[i];
      float dis = (d > 0) ? rsqrtf((float)d) : 0.0f;
      sdis[i] = dis;
      invdeg[node] = (d > 0) ? (1.0f / (float)d) : 0.0f;
      sdeg[node] = sqrtf((float)d);
    }
  }
  __syncthreads();
  int nloc = min(BKT_NODES, n - node0);
  const float4* ev = reinterpret_cast<const float4*>(emb);
  float4* zv = reinterpret_cast<float4*>(z0);
  for (int t = threadIdx.x; t < nloc * 16; t += blockDim.x) {
    int rrow = t >> 4, quad = t & 15;
    float4 v = ev[(size_t)(node0 + rrow) * 16 + quad];
    float dis = sdis[rrow];
    v.x *= dis; v.y *= dis; v.z *= dis; v.w *= dis;
    zv[(size_t)(node0 + rrow) * 16 + quad] = v;
  }
}

// one workgroup per bucket; 16 groups of 16 lanes, each group owns one edge
// at a time (lane covers 4 dims as float4); gather pipelined 2-deep.
template <bool FINAL>
__global__ __launch_bounds__(256)
void k_prop(const int* __restrict__ bcursor, const int* __restrict__ tmp,
            const float* __restrict__ z, float* __restrict__ zout,
            const float* __restrict__ invdeg, const float* __restrict__ emb,
            const float* __restrict__ z1, const float* __restrict__ z2,
            const float* __restrict__ sdeg, float* __restrict__ out, int n) {
  __shared__ float acc[BKT_NODES * 64];
  int b = blockIdx.x;
  int base = b * BKT_CAP;
  int cnt = bcursor[b] - base;
  float4* av = reinterpret_cast<float4*>(acc);
  for (int i = threadIdx.x; i < BKT_NODES * 16; i += blockDim.x)
    av[i] = make_float4(0.f, 0.f, 0.f, 0.f);
  __syncthreads();

  int g = threadIdx.x >> 4;
  int l = threadIdx.x & 15;
  const float4* zv = reinterpret_cast<const float4*>(z);

  int q0 = g;
  int rec0 = 0;
  float4 v0 = make_float4(0.f, 0.f, 0.f, 0.f);
  if (q0 < cnt) {
    rec0 = tmp[base + q0];
    v0 = zv[(size_t)(rec0 & 0xFFFFF) * 16 + l];
  }
  int q1 = q0 + 16;
  int rec1 = (q1 < cnt) ? tmp[base + q1] : 0;

  while (q0 < cnt) {
    float4 v1 = make_float4(0.f, 0.f, 0.f, 0.f);
    if (q1 < cnt) v1 = zv[(size_t)(rec1 & 0xFFFFF) * 16 + l];
    int q2 = q1 + 16;
    int rec2 = (q2 < cnt) ? tmp[base + q2] : 0;
    float* a = &acc[(rec0 >> 20) * 64 + l * 4];
    atomicAdd(a + 0, v0.x);
    atomicAdd(a + 1, v0.y);
    atomicAdd(a + 2, v0.z);
    atomicAdd(a + 3, v0.w);
    q0 = q1; rec0 = rec1; v0 = v1;
    q1 = q2; rec1 = rec2;
  }
  __syncthreads();

  int node0 = b << BKT_SHIFT;
  int nloc = min(BKT_NODES, n - node0);
  for (int t = threadIdx.x; t < nloc * 16; t += blockDim.x) {
    int rrow = t >> 4, quad = t & 15;
    int node = node0 + rrow;
    float idg = invdeg[node];
    float4 s = av[rrow * 16 + quad];
    s.x *= idg; s.y *= idg; s.z *= idg; s.w *= idg;
    size_t gi = (size_t)node * 16 + quad;
    if (!FINAL) {
      reinterpret_cast<float4*>(zout)[gi] = s;
    } else {
      float sd = sdeg[node];
      float4 e = reinterpret_cast<const float4*>(emb)[gi];
      float4 a1 = reinterpret_cast<const float4*>(z1)[gi];
      float4 a2 = reinterpret_cast<const float4*>(z2)[gi];
      float4 o;
      o.x = 0.25f * (e.x + sd * (a1.x + a2.x + s.x));
      o.y = 0.25f * (e.y + sd * (a1.y + a2.y + s.y));
      o.z = 0.25f * (e.z + sd * (a1.z + a2.z + s.z));
      o.w = 0.25f * (e.w + sd * (a1.w + a2.w + s.w));
      reinterpret_cast<float4*>(out)[gi] = o;
    }
  }
}

extern "C" void kernel_launch(void* const* d_in, const int* in_sizes, int n_in,
                              void* d_out, int out_size, void* d_ws, size_t ws_size,
                              hipStream_t stream) {
  const int* edge = (const int*)d_in[0];
  const float* emb = (const float*)d_in[1];
  float* out = (float*)d_out;

  const int E = in_sizes[0] / 2;
  const int n = in_sizes[1] / 64;
  const int* row = edge;        // sources j
  const int* col = edge + E;    // targets i
  const int NBKT = (n + BKT_NODES - 1) / BKT_NODES;   // 782

  char* ws = (char*)d_ws;
  size_t off = 0;
  auto alloc = [&](size_t bytes) -> void* {
    void* p = ws + off;
    off += (bytes + 255) & ~(size_t)255;
    return p;
  };
  int*   bcursor = (int*)  alloc((size_t)NBKT * 4);
  int*   tmp     = (int*)  alloc((size_t)NBKT * BKT_CAP * 4);   // 6.4 MB
  float* invdeg  = (float*)alloc((size_t)n * 4);
  float* sdeg    = (float*)alloc((size_t)n * 4);
  float* z0      = (float*)alloc((size_t)n * 64 * 4);
  float* z1      = (float*)alloc((size_t)n * 64 * 4);
  float* z2      = (float*)alloc((size_t)n * 64 * 4);
  (void)ws_size; (void)n_in; (void)out_size;

  k_init<<<(NBKT + 255) / 256, 256, 0, stream>>>(bcursor, NBKT);
  k_bin<<<(E + 255) / 256, 256, 0, stream>>>(row, col, bcursor, tmp, E);
  k_hist<<<NBKT, 256, 0, stream>>>(bcursor, tmp, emb, z0, invdeg, sdeg, n);

  k_prop<false><<<NBKT, 256, 0, stream>>>(bcursor, tmp, z0, z1, invdeg,
                                          nullptr, nullptr, nullptr, nullptr, nullptr, n);
  k_prop<false><<<NBKT, 256, 0, stream>>>(bcursor, tmp, z1, z2, invdeg,
                                          nullptr, nullptr, nullptr, nullptr, nullptr, n);
  k_prop<true ><<<NBKT, 256, 0, stream>>>(bcursor, tmp, z2, nullptr, invdeg,
                                          emb, z1, z2, sdeg, out, n);
}

// Round 4
// 202.969 us; speedup vs baseline: 9.3999x; 9.3999x over previous
//
#include <hip/hip_runtime.h>

// LightGCN, z-form: z = dis(.)x  =>  z_k[c] = invdeg_c * sum_{r->c} z_{k-1}[r]
//   out = 0.25*(emb + sdeg (.) (z1+z2+z3)),  sdeg = sqrt(deg), dis = 1/sdeg.
// Build: radix partition by target bucket (128 nodes) with LDS-aggregated
// histograms, then per-bucket counting sort -> per-node CSR (srcs only, 4B).
// Prop: one wave per node, 4 groups x 16 lanes, bf16 z gathers (128B rows),
// fp32 accumulate, shfl_xor(16,32) reduce. Final layer fuses the mean.

#define BKT_SHIFT 7
#define BKT_NODES 128
#define BKT_CAP   2048      // mean 1600 edges/bucket; +11 sigma headroom
#define EPB       8192      // edges per k_bin block

__device__ __forceinline__ float bf2f(unsigned short u) {
  return __uint_as_float(((unsigned)u) << 16);
}
__device__ __forceinline__ unsigned short f2bf(float f) {
  unsigned b = __float_as_uint(f);
  return (unsigned short)((b + 0x7FFF + ((b >> 16) & 1)) >> 16);  // RNE
}

__device__ __forceinline__ int wave_scan_incl(int v, int lane) {
#pragma unroll
  for (int off = 1; off < 64; off <<= 1) {
    int t = __shfl_up(v, off, 64);
    if (lane >= off) v += t;
  }
  return v;
}

__global__ void k_init(int* __restrict__ bcursor, int nbkt) {
  int i = blockIdx.x * blockDim.x + threadIdx.x;
  if (i < nbkt) bcursor[i] = i * BKT_CAP;
}

// radix partition by target bucket; LDS-aggregated so global atomics are
// one per (block, bin) and record writes are grouped per bin.
__global__ __launch_bounds__(256)
void k_bin(const int* __restrict__ row, const int* __restrict__ col,
           int* __restrict__ bcursor, int* __restrict__ tmp, int E, int nbkt) {
  __shared__ int h[1024];                 // nbkt <= 1024
  int e0 = blockIdx.x * EPB;
  int e1 = min(e0 + EPB, E);
  for (int i = threadIdx.x; i < nbkt; i += 256) h[i] = 0;
  __syncthreads();
  for (int e = e0 + threadIdx.x; e < e1; e += 256)
    atomicAdd(&h[col[e] >> BKT_SHIFT], 1);
  __syncthreads();
  for (int i = threadIdx.x; i < nbkt; i += 256) {
    int c = h[i];
    h[i] = c ? atomicAdd(&bcursor[i], c) : 0;   // reserve range, h -> base
  }
  __syncthreads();
  for (int e = e0 + threadIdx.x; e < e1; e += 256) {
    int c = col[e], r = row[e];
    int p = atomicAdd(&h[c >> BKT_SHIFT], 1);
    tmp[p] = r | ((c & (BKT_NODES - 1)) << 20);
  }
}

// per-bucket counting sort -> per-node CSR; also deg stats and z0 = bf16(dis*emb)
__global__ __launch_bounds__(256)
void k_sort(const int* __restrict__ bcursor, const int* __restrict__ tmp,
            int* __restrict__ srcs, int* __restrict__ obeg, int* __restrict__ oend,
            float* __restrict__ invdeg, float* __restrict__ sdeg,
            const float* __restrict__ emb, unsigned short* __restrict__ z0, int n) {
  __shared__ int hist[BKT_NODES];
  __shared__ int excl[BKT_NODES];
  __shared__ int cur[BKT_NODES];
  __shared__ float sdis[BKT_NODES];
  int b = blockIdx.x;
  int base = b * BKT_CAP;
  int cnt = bcursor[b] - base;
  if (threadIdx.x < BKT_NODES) hist[threadIdx.x] = 0;
  __syncthreads();
  for (int q = threadIdx.x; q < cnt; q += 256)
    atomicAdd(&hist[(unsigned)tmp[base + q] >> 20], 1);
  __syncthreads();
  if (threadIdx.x < 64) {                 // scan 128 bins: lane l owns 2l, 2l+1
    int l = threadIdx.x;
    int h0 = hist[2 * l], h1 = hist[2 * l + 1];
    int v = h0 + h1;
    int incl = wave_scan_incl(v, l);
    int ex = incl - v;
    excl[2 * l] = ex;      excl[2 * l + 1] = ex + h0;
    cur[2 * l] = ex;       cur[2 * l + 1] = ex + h0;
  }
  __syncthreads();
  int node0 = b << BKT_SHIFT;
  if (threadIdx.x < BKT_NODES) {
    int node = node0 + threadIdx.x;
    if (node < n) {
      int d = hist[threadIdx.x];
      int bg = base + excl[threadIdx.x];
      obeg[node] = bg;
      oend[node] = bg + d;
      float fd = (float)d;
      invdeg[node] = d ? 1.0f / fd : 0.0f;
      sdeg[node] = sqrtf(fd);
      sdis[threadIdx.x] = d ? rsqrtf(fd) : 0.0f;
    } else {
      sdis[threadIdx.x] = 0.0f;
    }
  }
  __syncthreads();
  for (int q = threadIdx.x; q < cnt; q += 256) {
    int rec = tmp[base + q];
    int lc = (unsigned)rec >> 20;
    int p = atomicAdd(&cur[lc], 1);
    srcs[base + p] = rec & 0xFFFFF;
  }
  int nloc = min(BKT_NODES, n - node0);
  for (int t = threadIdx.x; t < nloc * 16; t += 256) {
    int rr = t >> 4, q = t & 15;
    float4 v = reinterpret_cast<const float4*>(emb)[(size_t)(node0 + rr) * 16 + q];
    float ds = sdis[rr];
    ushort4 o;
    o.x = f2bf(v.x * ds); o.y = f2bf(v.y * ds);
    o.z = f2bf(v.z * ds); o.w = f2bf(v.w * ds);
    reinterpret_cast<ushort4*>(z0)[(size_t)(node0 + rr) * 16 + q] = o;
  }
}

// one wave per node; group g of 16 lanes handles edges beg+g, +4, ...; lane
// covers 4 dims (bf16x4 = 8B, 16 lanes = full 128B row). 1-deep src prefetch.
template <bool FINAL>
__global__ __launch_bounds__(256)
void k_prop(const int* __restrict__ obeg, const int* __restrict__ oend,
            const int* __restrict__ srcs, const unsigned short* __restrict__ z,
            unsigned short* __restrict__ zout, const float* __restrict__ invdeg,
            const float* __restrict__ emb, const unsigned short* __restrict__ z1,
            const unsigned short* __restrict__ z2, const float* __restrict__ sdeg,
            float* __restrict__ out, int n) {
  int lane = threadIdx.x & 63;
  int node = blockIdx.x * (blockDim.x >> 6) + (threadIdx.x >> 6);
  if (node >= n) return;
  int g = lane >> 4, l = lane & 15;
  int beg = obeg[node], end = oend[node];
  const ushort4* zv = reinterpret_cast<const ushort4*>(z);
  size_t gi = (size_t)node * 16 + l;

  float4 t = make_float4(0.f, 0.f, 0.f, 0.f);   // final-layer side terms
  if (FINAL) {
    if (g == 1) {
      t = reinterpret_cast<const float4*>(emb)[gi];
    } else if (g == 2) {
      ushort4 a1 = reinterpret_cast<const ushort4*>(z1)[gi];
      ushort4 a2 = reinterpret_cast<const ushort4*>(z2)[gi];
      float sd = sdeg[node];
      t.x = sd * (bf2f(a1.x) + bf2f(a2.x));
      t.y = sd * (bf2f(a1.y) + bf2f(a2.y));
      t.z = sd * (bf2f(a1.z) + bf2f(a2.z));
      t.w = sd * (bf2f(a1.w) + bf2f(a2.w));
    }
  }

  float4 s = make_float4(0.f, 0.f, 0.f, 0.f);
  int k = beg + g;
  int src = (k < end) ? srcs[k] : 0;
  while (k < end) {
    int k2 = k + 4;
    int src2 = (k2 < end) ? srcs[k2] : 0;
    ushort4 zr = zv[(size_t)src * 16 + l];
    s.x += bf2f(zr.x); s.y += bf2f(zr.y); s.z += bf2f(zr.z); s.w += bf2f(zr.w);
    k = k2; src = src2;
  }
#pragma unroll
  for (int off = 16; off < 64; off <<= 1) {
    s.x += __shfl_xor(s.x, off, 64);
    s.y += __shfl_xor(s.y, off, 64);
    s.z += __shfl_xor(s.z, off, 64);
    s.w += __shfl_xor(s.w, off, 64);
    if (FINAL) {
      t.x += __shfl_xor(t.x, off, 64);
      t.y += __shfl_xor(t.y, off, 64);
      t.z += __shfl_xor(t.z, off, 64);
      t.w += __shfl_xor(t.w, off, 64);
    }
  }
  if (g == 0) {
    float idg = invdeg[node];
    if (!FINAL) {
      ushort4 o;
      o.x = f2bf(s.x * idg); o.y = f2bf(s.y * idg);
      o.z = f2bf(s.z * idg); o.w = f2bf(s.w * idg);
      reinterpret_cast<ushort4*>(zout)[gi] = o;
    } else {
      float c = sdeg[node] * idg;       // out = 0.25*(t + sdeg*invdeg*S)
      float4 o;
      o.x = 0.25f * (t.x + c * s.x);
      o.y = 0.25f * (t.y + c * s.y);
      o.z = 0.25f * (t.z + c * s.z);
      o.w = 0.25f * (t.w + c * s.w);
      reinterpret_cast<float4*>(out)[gi] = o;
    }
  }
}

extern "C" void kernel_launch(void* const* d_in, const int* in_sizes, int n_in,
                              void* d_out, int out_size, void* d_ws, size_t ws_size,
                              hipStream_t stream) {
  const int* edge = (const int*)d_in[0];
  const float* emb = (const float*)d_in[1];
  float* out = (float*)d_out;

  const int E = in_sizes[0] / 2;
  const int n = in_sizes[1] / 64;
  const int* row = edge;        // sources j
  const int* col = edge + E;    // targets i
  const int NBKT = (n + BKT_NODES - 1) / BKT_NODES;   // 782

  char* ws = (char*)d_ws;
  size_t off = 0;
  auto alloc = [&](size_t bytes) -> void* {
    void* p = ws + off;
    off += (bytes + 255) & ~(size_t)255;
    return p;
  };
  int*   bcursor = (int*)  alloc((size_t)NBKT * 4);
  int*   tmp     = (int*)  alloc((size_t)NBKT * BKT_CAP * 4);   // 6.4 MB
  int*   srcs    = (int*)  alloc((size_t)NBKT * BKT_CAP * 4);   // 6.4 MB
  int*   obeg    = (int*)  alloc((size_t)n * 4);
  int*   oend    = (int*)  alloc((size_t)n * 4);
  float* invdeg  = (float*)alloc((size_t)n * 4);
  float* sdeg    = (float*)alloc((size_t)n * 4);
  unsigned short* z0 = (unsigned short*)alloc((size_t)n * 64 * 2);
  unsigned short* z1 = (unsigned short*)alloc((size_t)n * 64 * 2);
  unsigned short* z2 = (unsigned short*)alloc((size_t)n * 64 * 2);
  (void)ws_size; (void)n_in; (void)out_size;

  const int NBB = (E + EPB - 1) / EPB;    // 153
  k_init<<<(NBKT + 255) / 256, 256, 0, stream>>>(bcursor, NBKT);
  k_bin<<<NBB, 256, 0, stream>>>(row, col, bcursor, tmp, E, NBKT);
  k_sort<<<NBKT, 256, 0, stream>>>(bcursor, tmp, srcs, obeg, oend,
                                   invdeg, sdeg, emb, z0, n);

  const int pg = (n + 3) / 4;             // 4 nodes (waves) per 256-thread block
  k_prop<false><<<pg, 256, 0, stream>>>(obeg, oend, srcs, z0, z1, invdeg,
                                        nullptr, nullptr, nullptr, nullptr, nullptr, n);
  k_prop<false><<<pg, 256, 0, stream>>>(obeg, oend, srcs, z1, z2, invdeg,
                                        nullptr, nullptr, nullptr, nullptr, nullptr, n);
  k_prop<true ><<<pg, 256, 0, stream>>>(obeg, oend, srcs, z2, nullptr, invdeg,
                                        emb, z1, z2, sdeg, out, n);
}

// Round 5
// 156.914 us; speedup vs baseline: 12.1588x; 1.2935x over previous
//
#include <hip/hip_runtime.h>

// LightGCN, z-form: z = dis(.)x  =>  z_k[c] = invdeg_c * sum_{r->c} z_{k-1}[r]
//   out = 0.25*(emb + sdeg (.) (z1+z2+z3)),  sdeg = sqrt(deg), dis = 1/sdeg.
// Build: radix partition by target bucket (128 nodes) with LDS-aggregated
// histograms, then per-bucket counting sort -> per-node CSR (srcs only, 4B).
// Prop: one wave per node, 8 groups x 8 lanes (lane = uint4 = 8 bf16 dims),
// 2 edges unrolled per group (up to 16 gathers in flight per wave),
// fp32 accumulate, shfl_xor(8,16,32) reduce. Final layer fuses the mean.

#define BKT_SHIFT 7
#define BKT_NODES 128
#define BKT_CAP   2048      // mean 1600 edges/bucket; +11 sigma headroom
#define EPB       8192      // edges per k_bin block

__device__ __forceinline__ unsigned short f2bf(float f) {
  unsigned b = __float_as_uint(f);
  return (unsigned short)((b + 0x7FFF + ((b >> 16) & 1)) >> 16);  // RNE
}
__device__ __forceinline__ float lo2f(unsigned u) { return __uint_as_float(u << 16); }
__device__ __forceinline__ float hi2f(unsigned u) { return __uint_as_float(u & 0xFFFF0000u); }
__device__ __forceinline__ unsigned packbf(float a, float b) {
  return (unsigned)f2bf(a) | ((unsigned)f2bf(b) << 16);
}

__device__ __forceinline__ int wave_scan_incl(int v, int lane) {
#pragma unroll
  for (int off = 1; off < 64; off <<= 1) {
    int t = __shfl_up(v, off, 64);
    if (lane >= off) v += t;
  }
  return v;
}

__global__ void k_init(int* __restrict__ bcursor, int nbkt) {
  int i = blockIdx.x * blockDim.x + threadIdx.x;
  if (i < nbkt) bcursor[i] = i * BKT_CAP;
}

// radix partition by target bucket; LDS-aggregated so global atomics are
// one per (block, bin) and record writes are grouped per bin.
__global__ __launch_bounds__(256)
void k_bin(const int* __restrict__ row, const int* __restrict__ col,
           int* __restrict__ bcursor, int* __restrict__ tmp, int E, int nbkt) {
  __shared__ int h[1024];                 // nbkt <= 1024
  int e0 = blockIdx.x * EPB;
  int e1 = min(e0 + EPB, E);
  for (int i = threadIdx.x; i < nbkt; i += 256) h[i] = 0;
  __syncthreads();
  for (int e = e0 + threadIdx.x; e < e1; e += 256)
    atomicAdd(&h[col[e] >> BKT_SHIFT], 1);
  __syncthreads();
  for (int i = threadIdx.x; i < nbkt; i += 256) {
    int c = h[i];
    h[i] = c ? atomicAdd(&bcursor[i], c) : 0;   // reserve range, h -> base
  }
  __syncthreads();
  for (int e = e0 + threadIdx.x; e < e1; e += 256) {
    int c = col[e], r = row[e];
    int p = atomicAdd(&h[c >> BKT_SHIFT], 1);
    tmp[p] = r | ((c & (BKT_NODES - 1)) << 20);
  }
}

// per-bucket counting sort -> per-node CSR; also deg stats and z0 = bf16(dis*emb)
__global__ __launch_bounds__(256)
void k_sort(const int* __restrict__ bcursor, const int* __restrict__ tmp,
            int* __restrict__ srcs, int* __restrict__ obeg, int* __restrict__ oend,
            float* __restrict__ invdeg, float* __restrict__ sdeg,
            const float* __restrict__ emb, unsigned short* __restrict__ z0, int n) {
  __shared__ int hist[BKT_NODES];
  __shared__ int excl[BKT_NODES];
  __shared__ int cur[BKT_NODES];
  __shared__ float sdis[BKT_NODES];
  int b = blockIdx.x;
  int base = b * BKT_CAP;
  int cnt = bcursor[b] - base;
  if (threadIdx.x < BKT_NODES) hist[threadIdx.x] = 0;
  __syncthreads();
  for (int q = threadIdx.x; q < cnt; q += 256)
    atomicAdd(&hist[(unsigned)tmp[base + q] >> 20], 1);
  __syncthreads();
  if (threadIdx.x < 64) {                 // scan 128 bins: lane l owns 2l, 2l+1
    int l = threadIdx.x;
    int h0 = hist[2 * l], h1 = hist[2 * l + 1];
    int v = h0 + h1;
    int incl = wave_scan_incl(v, l);
    int ex = incl - v;
    excl[2 * l] = ex;      excl[2 * l + 1] = ex + h0;
    cur[2 * l] = ex;       cur[2 * l + 1] = ex + h0;
  }
  __syncthreads();
  int node0 = b << BKT_SHIFT;
  if (threadIdx.x < BKT_NODES) {
    int node = node0 + threadIdx.x;
    if (node < n) {
      int d = hist[threadIdx.x];
      int bg = base + excl[threadIdx.x];
      obeg[node] = bg;
      oend[node] = bg + d;
      float fd = (float)d;
      invdeg[node] = d ? 1.0f / fd : 0.0f;
      sdeg[node] = sqrtf(fd);
      sdis[threadIdx.x] = d ? rsqrtf(fd) : 0.0f;
    } else {
      sdis[threadIdx.x] = 0.0f;
    }
  }
  __syncthreads();
  for (int q = threadIdx.x; q < cnt; q += 256) {
    int rec = tmp[base + q];
    int lc = (unsigned)rec >> 20;
    int p = atomicAdd(&cur[lc], 1);
    srcs[base + p] = rec & 0xFFFFF;
  }
  int nloc = min(BKT_NODES, n - node0);
  for (int t = threadIdx.x; t < nloc * 16; t += 256) {
    int rr = t >> 4, q = t & 15;
    float4 v = reinterpret_cast<const float4*>(emb)[(size_t)(node0 + rr) * 16 + q];
    float ds = sdis[rr];
    ushort4 o;
    o.x = f2bf(v.x * ds); o.y = f2bf(v.y * ds);
    o.z = f2bf(v.z * ds); o.w = f2bf(v.w * ds);
    reinterpret_cast<ushort4*>(z0)[(size_t)(node0 + rr) * 16 + q] = o;
  }
}

// one wave per node; 8 groups of 8 lanes; group g handles edges beg+g, +8, ...
// unrolled 2-wide (A at k, B at k+8). lane l covers dims 8l..8l+7 as uint4.
template <bool FINAL>
__global__ __launch_bounds__(256)
void k_prop(const int* __restrict__ obeg, const int* __restrict__ oend,
            const int* __restrict__ srcs, const unsigned short* __restrict__ z,
            unsigned short* __restrict__ zout, const float* __restrict__ invdeg,
            const float* __restrict__ emb, const unsigned short* __restrict__ z1,
            const unsigned short* __restrict__ z2, const float* __restrict__ sdeg,
            float* __restrict__ out, int n) {
  int lane = threadIdx.x & 63;
  int node = blockIdx.x * (blockDim.x >> 6) + (threadIdx.x >> 6);
  if (node >= n) return;
  int g = lane >> 3, l = lane & 7;
  int beg = obeg[node], end = oend[node];
  const uint4* zv = reinterpret_cast<const uint4*>(z);   // row = 8 x uint4

  float s0 = 0.f, s1 = 0.f, s2 = 0.f, s3 = 0.f;
  float s4 = 0.f, s5 = 0.f, s6 = 0.f, s7 = 0.f;

  int k = beg + g;
  int srcA = (k < end) ? srcs[k] : 0;
  int srcB = (k + 8 < end) ? srcs[k + 8] : 0;
  while (k < end) {
    bool hasB = (k + 8) < end;
    uint4 a = zv[(size_t)srcA * 8 + l];
    uint4 bb;
    if (hasB) bb = zv[(size_t)srcB * 8 + l];
    int k2 = k + 16;
    srcA = (k2 < end) ? srcs[k2] : 0;
    srcB = (k2 + 8 < end) ? srcs[k2 + 8] : 0;
    s0 += lo2f(a.x); s1 += hi2f(a.x); s2 += lo2f(a.y); s3 += hi2f(a.y);
    s4 += lo2f(a.z); s5 += hi2f(a.z); s6 += lo2f(a.w); s7 += hi2f(a.w);
    if (hasB) {
      s0 += lo2f(bb.x); s1 += hi2f(bb.x); s2 += lo2f(bb.y); s3 += hi2f(bb.y);
      s4 += lo2f(bb.z); s5 += hi2f(bb.z); s6 += lo2f(bb.w); s7 += hi2f(bb.w);
    }
    k = k2;
  }
#pragma unroll
  for (int off = 8; off < 64; off <<= 1) {
    s0 += __shfl_xor(s0, off, 64);
    s1 += __shfl_xor(s1, off, 64);
    s2 += __shfl_xor(s2, off, 64);
    s3 += __shfl_xor(s3, off, 64);
    s4 += __shfl_xor(s4, off, 64);
    s5 += __shfl_xor(s5, off, 64);
    s6 += __shfl_xor(s6, off, 64);
    s7 += __shfl_xor(s7, off, 64);
  }
  if (g == 0) {
    float idg = invdeg[node];
    if (!FINAL) {
      uint4 o;
      o.x = packbf(s0 * idg, s1 * idg);
      o.y = packbf(s2 * idg, s3 * idg);
      o.z = packbf(s4 * idg, s5 * idg);
      o.w = packbf(s6 * idg, s7 * idg);
      reinterpret_cast<uint4*>(zout)[(size_t)node * 8 + l] = o;
    } else {
      float sd = sdeg[node];
      float c = sd * idg;
      uint4 a1 = reinterpret_cast<const uint4*>(z1)[(size_t)node * 8 + l];
      uint4 a2 = reinterpret_cast<const uint4*>(z2)[(size_t)node * 8 + l];
      float4 e0 = reinterpret_cast<const float4*>(emb)[(size_t)node * 16 + 2 * l];
      float4 e1 = reinterpret_cast<const float4*>(emb)[(size_t)node * 16 + 2 * l + 1];
      float4 o0, o1;
      o0.x = 0.25f * (e0.x + sd * (lo2f(a1.x) + lo2f(a2.x)) + c * s0);
      o0.y = 0.25f * (e0.y + sd * (hi2f(a1.x) + hi2f(a2.x)) + c * s1);
      o0.z = 0.25f * (e0.z + sd * (lo2f(a1.y) + lo2f(a2.y)) + c * s2);
      o0.w = 0.25f * (e0.w + sd * (hi2f(a1.y) + hi2f(a2.y)) + c * s3);
      o1.x = 0.25f * (e1.x + sd * (lo2f(a1.z) + lo2f(a2.z)) + c * s4);
      o1.y = 0.25f * (e1.y + sd * (hi2f(a1.z) + hi2f(a2.z)) + c * s5);
      o1.z = 0.25f * (e1.z + sd * (lo2f(a1.w) + lo2f(a2.w)) + c * s6);
      o1.w = 0.25f * (e1.w + sd * (hi2f(a1.w) + hi2f(a2.w)) + c * s7);
      reinterpret_cast<float4*>(out)[(size_t)node * 16 + 2 * l] = o0;
      reinterpret_cast<float4*>(out)[(size_t)node * 16 + 2 * l + 1] = o1;
    }
  }
}

extern "C" void kernel_launch(void* const* d_in, const int* in_sizes, int n_in,
                              void* d_out, int out_size, void* d_ws, size_t ws_size,
                              hipStream_t stream) {
  const int* edge = (const int*)d_in[0];
  const float* emb = (const float*)d_in[1];
  float* out = (float*)d_out;

  const int E = in_sizes[0] / 2;
  const int n = in_sizes[1] / 64;
  const int* row = edge;        // sources j
  const int* col = edge + E;    // targets i
  const int NBKT = (n + BKT_NODES - 1) / BKT_NODES;   // 782

  char* ws = (char*)d_ws;
  size_t off = 0;
  auto alloc = [&](size_t bytes) -> void* {
    void* p = ws + off;
    off += (bytes + 255) & ~(size_t)255;
    return p;
  };
  int*   bcursor = (int*)  alloc((size_t)NBKT * 4);
  int*   tmp     = (int*)  alloc((size_t)NBKT * BKT_CAP * 4);   // 6.4 MB
  int*   srcs    = (int*)  alloc((size_t)NBKT * BKT_CAP * 4);   // 6.4 MB
  int*   obeg    = (int*)  alloc((size_t)n * 4);
  int*   oend    = (int*)  alloc((size_t)n * 4);
  float* invdeg  = (float*)alloc((size_t)n * 4);
  float* sdeg    = (float*)alloc((size_t)n * 4);
  unsigned short* z0 = (unsigned short*)alloc((size_t)n * 64 * 2);
  unsigned short* z1 = (unsigned short*)alloc((size_t)n * 64 * 2);
  unsigned short* z2 = (unsigned short*)alloc((size_t)n * 64 * 2);
  (void)ws_size; (void)n_in; (void)out_size;

  const int NBB = (E + EPB - 1) / EPB;    // 153
  k_init<<<(NBKT + 255) / 256, 256, 0, stream>>>(bcursor, NBKT);
  k_bin<<<NBB, 256, 0, stream>>>(row, col, bcursor, tmp, E, NBKT);
  k_sort<<<NBKT, 256, 0, stream>>>(bcursor, tmp, srcs, obeg, oend,
                                   invdeg, sdeg, emb, z0, n);

  const int pg = (n + 3) / 4;             // 4 nodes (waves) per 256-thread block
  k_prop<false><<<pg, 256, 0, stream>>>(obeg, oend, srcs, z0, z1, invdeg,
                                        nullptr, nullptr, nullptr, nullptr, nullptr, n);
  k_prop<false><<<pg, 256, 0, stream>>>(obeg, oend, srcs, z1, z2, invdeg,
                                        nullptr, nullptr, nullptr, nullptr, nullptr, n);
  k_prop<true ><<<pg, 256, 0, stream>>>(obeg, oend, srcs, z2, nullptr, invdeg,
                                        emb, z1, z2, sdeg, out, n);
}

// Round 6
// 131.799 us; speedup vs baseline: 14.4758x; 1.1906x over previous
//
#include <hip/hip_runtime.h>

// LightGCN, z-form: z = dis(.)x  =>  z_k[c] = invdeg_c * sum_{r->c} z_{k-1}[r]
//   out = 0.25*(emb + sdeg (.) (z1+z2+z3)),  sdeg = sqrt(deg), dis = 1/sdeg.
// Build: radix partition by target bucket (128 nodes) with LDS-aggregated
// histograms, then per-bucket counting sort -> per-node CSR (srcs only, 4B).
// Prop: 8-lane group per node (8 nodes/wave), lane = uint4 = 8 bf16 dims,
// serial edge walk with 2-edge unroll (16 gathers in flight per wave),
// NO cross-lane reduce. bf16 pack via v_cvt_pk_bf16_f32.

#define BKT_SHIFT 7
#define BKT_NODES 128
#define BKT_CAP   2048      // mean 1600 edges/bucket; +11 sigma headroom
#define EPB       2048      // edges per k_bin block (611 blocks)

__device__ __forceinline__ float lo2f(unsigned u) { return __uint_as_float(u << 16); }
__device__ __forceinline__ float hi2f(unsigned u) { return __uint_as_float(u & 0xFFFF0000u); }
__device__ __forceinline__ unsigned cvt_pk_bf16(float lo, float hi) {
  unsigned r;
  asm("v_cvt_pk_bf16_f32 %0, %1, %2" : "=v"(r) : "v"(lo), "v"(hi));
  return r;
}

__device__ __forceinline__ int wave_scan_incl(int v, int lane) {
#pragma unroll
  for (int off = 1; off < 64; off <<= 1) {
    int t = __shfl_up(v, off, 64);
    if (lane >= off) v += t;
  }
  return v;
}

__global__ void k_init(int* __restrict__ bcursor, int nbkt) {
  int i = blockIdx.x * blockDim.x + threadIdx.x;
  if (i < nbkt) bcursor[i] = i * BKT_CAP;
}

// radix partition by target bucket; LDS-aggregated so global atomics are
// one per (block, bin) and record writes are grouped per bin.
__global__ __launch_bounds__(256)
void k_bin(const int* __restrict__ row, const int* __restrict__ col,
           int* __restrict__ bcursor, int* __restrict__ tmp, int E, int nbkt) {
  __shared__ int h[1024];                 // nbkt <= 1024
  int e0 = blockIdx.x * EPB;
  int e1 = min(e0 + EPB, E);
  for (int i = threadIdx.x; i < nbkt; i += 256) h[i] = 0;
  __syncthreads();
  for (int e = e0 + threadIdx.x; e < e1; e += 256)
    atomicAdd(&h[col[e] >> BKT_SHIFT], 1);
  __syncthreads();
  for (int i = threadIdx.x; i < nbkt; i += 256) {
    int c = h[i];
    h[i] = c ? atomicAdd(&bcursor[i], c) : 0;   // reserve range, h -> base
  }
  __syncthreads();
  for (int e = e0 + threadIdx.x; e < e1; e += 256) {
    int c = col[e], r = row[e];
    int p = atomicAdd(&h[c >> BKT_SHIFT], 1);
    tmp[p] = r | ((c & (BKT_NODES - 1)) << 20);
  }
}

// per-bucket counting sort -> per-node CSR; also deg stats and z0 = bf16(dis*emb)
__global__ __launch_bounds__(256)
void k_sort(const int* __restrict__ bcursor, const int* __restrict__ tmp,
            int* __restrict__ srcs, int* __restrict__ obeg, int* __restrict__ oend,
            float* __restrict__ invdeg, float* __restrict__ sdeg,
            const float* __restrict__ emb, unsigned short* __restrict__ z0, int n) {
  __shared__ int hist[BKT_NODES];
  __shared__ int excl[BKT_NODES];
  __shared__ int cur[BKT_NODES];
  __shared__ float sdis[BKT_NODES];
  int b = blockIdx.x;
  int base = b * BKT_CAP;
  int cnt = bcursor[b] - base;
  if (threadIdx.x < BKT_NODES) hist[threadIdx.x] = 0;
  __syncthreads();
  for (int q = threadIdx.x; q < cnt; q += 256)
    atomicAdd(&hist[(unsigned)tmp[base + q] >> 20], 1);
  __syncthreads();
  if (threadIdx.x < 64) {                 // scan 128 bins: lane l owns 2l, 2l+1
    int l = threadIdx.x;
    int h0 = hist[2 * l], h1 = hist[2 * l + 1];
    int v = h0 + h1;
    int incl = wave_scan_incl(v, l);
    int ex = incl - v;
    excl[2 * l] = ex;      excl[2 * l + 1] = ex + h0;
    cur[2 * l] = ex;       cur[2 * l + 1] = ex + h0;
  }
  __syncthreads();
  int node0 = b << BKT_SHIFT;
  if (threadIdx.x < BKT_NODES) {
    int node = node0 + threadIdx.x;
    if (node < n) {
      int d = hist[threadIdx.x];
      int bg = base + excl[threadIdx.x];
      obeg[node] = bg;
      oend[node] = bg + d;
      float fd = (float)d;
      invdeg[node] = d ? 1.0f / fd : 0.0f;
      sdeg[node] = sqrtf(fd);
      sdis[threadIdx.x] = d ? rsqrtf(fd) : 0.0f;
    } else {
      sdis[threadIdx.x] = 0.0f;
    }
  }
  __syncthreads();
  for (int q = threadIdx.x; q < cnt; q += 256) {
    int rec = tmp[base + q];
    int lc = (unsigned)rec >> 20;
    int p = atomicAdd(&cur[lc], 1);
    srcs[base + p] = rec & 0xFFFFF;
  }
  int nloc = min(BKT_NODES, n - node0);
  for (int t = threadIdx.x; t < nloc * 8; t += 256) {
    int rr = t >> 3, q = t & 7;
    float ds = sdis[rr];
    float4 v0 = reinterpret_cast<const float4*>(emb)[(size_t)(node0 + rr) * 16 + 2 * q];
    float4 v1 = reinterpret_cast<const float4*>(emb)[(size_t)(node0 + rr) * 16 + 2 * q + 1];
    uint4 o;
    o.x = cvt_pk_bf16(v0.x * ds, v0.y * ds);
    o.y = cvt_pk_bf16(v0.z * ds, v0.w * ds);
    o.z = cvt_pk_bf16(v1.x * ds, v1.y * ds);
    o.w = cvt_pk_bf16(v1.z * ds, v1.w * ds);
    reinterpret_cast<uint4*>(z0)[(size_t)(node0 + rr) * 8 + q] = o;
  }
}

// 8-lane group per node, 8 nodes per wave; lane l covers dims 8l..8l+7 (uint4).
// Serial edge walk per group, 2-edge unroll. No cross-lane reduce.
template <bool FINAL>
__global__ __launch_bounds__(256)
void k_prop(const int* __restrict__ obeg, const int* __restrict__ oend,
            const int* __restrict__ srcs, const unsigned short* __restrict__ z,
            unsigned short* __restrict__ zout, const float* __restrict__ invdeg,
            const float* __restrict__ emb, const unsigned short* __restrict__ z1,
            const unsigned short* __restrict__ z2, const float* __restrict__ sdeg,
            float* __restrict__ out, int n) {
  int lane = threadIdx.x & 63;
  int wid = (blockIdx.x * blockDim.x + threadIdx.x) >> 6;   // global wave id
  int g = lane >> 3, l = lane & 7;
  int node = wid * 8 + g;
  if (node >= n) return;
  int beg = obeg[node], end = oend[node];
  const uint4* zv = reinterpret_cast<const uint4*>(z);   // row = 8 x uint4

  float s0 = 0.f, s1 = 0.f, s2 = 0.f, s3 = 0.f;
  float s4 = 0.f, s5 = 0.f, s6 = 0.f, s7 = 0.f;

  int k = beg;
  int srcA = (k < end) ? srcs[k] : 0;
  int srcB = (k + 1 < end) ? srcs[k + 1] : 0;
  while (k < end) {
    bool hasB = (k + 1) < end;
    uint4 a = zv[(size_t)srcA * 8 + l];
    uint4 bb;
    if (hasB) bb = zv[(size_t)srcB * 8 + l];
    k += 2;
    srcA = (k < end) ? srcs[k] : 0;
    srcB = (k + 1 < end) ? srcs[k + 1] : 0;
    s0 += lo2f(a.x); s1 += hi2f(a.x); s2 += lo2f(a.y); s3 += hi2f(a.y);
    s4 += lo2f(a.z); s5 += hi2f(a.z); s6 += lo2f(a.w); s7 += hi2f(a.w);
    if (hasB) {
      s0 += lo2f(bb.x); s1 += hi2f(bb.x); s2 += lo2f(bb.y); s3 += hi2f(bb.y);
      s4 += lo2f(bb.z); s5 += hi2f(bb.z); s6 += lo2f(bb.w); s7 += hi2f(bb.w);
    }
  }

  float idg = invdeg[node];
  size_t gi = (size_t)node * 8 + l;
  if (!FINAL) {
    uint4 o;
    o.x = cvt_pk_bf16(s0 * idg, s1 * idg);
    o.y = cvt_pk_bf16(s2 * idg, s3 * idg);
    o.z = cvt_pk_bf16(s4 * idg, s5 * idg);
    o.w = cvt_pk_bf16(s6 * idg, s7 * idg);
    reinterpret_cast<uint4*>(zout)[gi] = o;
  } else {
    float sd = sdeg[node];
    float c = sd * idg;
    uint4 a1 = reinterpret_cast<const uint4*>(z1)[gi];
    uint4 a2 = reinterpret_cast<const uint4*>(z2)[gi];
    float4 e0 = reinterpret_cast<const float4*>(emb)[(size_t)node * 16 + 2 * l];
    float4 e1 = reinterpret_cast<const float4*>(emb)[(size_t)node * 16 + 2 * l + 1];
    float4 o0, o1;
    o0.x = 0.25f * (e0.x + sd * (lo2f(a1.x) + lo2f(a2.x)) + c * s0);
    o0.y = 0.25f * (e0.y + sd * (hi2f(a1.x) + hi2f(a2.x)) + c * s1);
    o0.z = 0.25f * (e0.z + sd * (lo2f(a1.y) + lo2f(a2.y)) + c * s2);
    o0.w = 0.25f * (e0.w + sd * (hi2f(a1.y) + hi2f(a2.y)) + c * s3);
    o1.x = 0.25f * (e1.x + sd * (lo2f(a1.z) + lo2f(a2.z)) + c * s4);
    o1.y = 0.25f * (e1.y + sd * (hi2f(a1.z) + hi2f(a2.z)) + c * s5);
    o1.z = 0.25f * (e1.z + sd * (lo2f(a1.w) + lo2f(a2.w)) + c * s6);
    o1.w = 0.25f * (e1.w + sd * (hi2f(a1.w) + hi2f(a2.w)) + c * s7);
    reinterpret_cast<float4*>(out)[(size_t)node * 16 + 2 * l] = o0;
    reinterpret_cast<float4*>(out)[(size_t)node * 16 + 2 * l + 1] = o1;
  }
}

extern "C" void kernel_launch(void* const* d_in, const int* in_sizes, int n_in,
                              void* d_out, int out_size, void* d_ws, size_t ws_size,
                              hipStream_t stream) {
  const int* edge = (const int*)d_in[0];
  const float* emb = (const float*)d_in[1];
  float* out = (float*)d_out;

  const int E = in_sizes[0] / 2;
  const int n = in_sizes[1] / 64;
  const int* row = edge;        // sources j
  const int* col = edge + E;    // targets i
  const int NBKT = (n + BKT_NODES - 1) / BKT_NODES;   // 782

  char* ws = (char*)d_ws;
  size_t off = 0;
  auto alloc = [&](size_t bytes) -> void* {
    void* p = ws + off;
    off += (bytes + 255) & ~(size_t)255;
    return p;
  };
  int*   bcursor = (int*)  alloc((size_t)NBKT * 4);
  int*   tmp     = (int*)  alloc((size_t)NBKT * BKT_CAP * 4);   // 6.4 MB
  int*   srcs    = (int*)  alloc((size_t)NBKT * BKT_CAP * 4);   // 6.4 MB
  int*   obeg    = (int*)  alloc((size_t)n * 4);
  int*   oend    = (int*)  alloc((size_t)n * 4);
  float* invdeg  = (float*)alloc((size_t)n * 4);
  float* sdeg    = (float*)alloc((size_t)n * 4);
  unsigned short* z0 = (unsigned short*)alloc((size_t)n * 64 * 2);
  unsigned short* z1 = (unsigned short*)alloc((size_t)n * 64 * 2);
  unsigned short* z2 = (unsigned short*)alloc((size_t)n * 64 * 2);
  (void)ws_size; (void)n_in; (void)out_size;

  const int NBB = (E + EPB - 1) / EPB;    // 611
  k_init<<<(NBKT + 255) / 256, 256, 0, stream>>>(bcursor, NBKT);
  k_bin<<<NBB, 256, 0, stream>>>(row, col, bcursor, tmp, E, NBKT);
  k_sort<<<NBKT, 256, 0, stream>>>(bcursor, tmp, srcs, obeg, oend,
                                   invdeg, sdeg, emb, z0, n);

  // 8 nodes per wave, 4 waves per block = 32 nodes/block
  const int pg = (n + 31) / 32;
  k_prop<false><<<pg, 256, 0, stream>>>(obeg, oend, srcs, z0, z1, invdeg,
                                        nullptr, nullptr, nullptr, nullptr, nullptr, n);
  k_prop<false><<<pg, 256, 0, stream>>>(obeg, oend, srcs, z1, z2, invdeg,
                                        nullptr, nullptr, nullptr, nullptr, nullptr, n);
  k_prop<true ><<<pg, 256, 0, stream>>>(obeg, oend, srcs, z2, nullptr, invdeg,
                                        emb, z1, z2, sdeg, out, n);
}

// Round 7
// 128.957 us; speedup vs baseline: 14.7948x; 1.0220x over previous
//
#include <hip/hip_runtime.h>

// LightGCN, z-form: z = dis(.)x  =>  z_k[c] = invdeg_c * sum_{r->c} z_{k-1}[r]
//   out = 0.25*(emb + sdeg (.) (z1+z2+z3)),  sdeg = sqrt(deg), dis = 1/sdeg.
// Build: radix partition by target bucket (128 nodes), per-bucket counting
// sort -> per-node CSR PADDED to multiple of 4 (dummy src = n -> zero row).
// Prop: 8-lane group per node (8 nodes/wave), lane = uint4 = 8 bf16 dims,
// guard-free 4-edge unroll (32 gathers in flight/wave), int4 src loads,
// fp32 accumulate, no cross-lane reduce. bf16 pack via v_cvt_pk_bf16_f32.

#define BKT_SHIFT 7
#define BKT_NODES 128
#define BKT_CAP   2560      // mean 1600 edges/bucket + pad(<=384) + slack
#define EPB       2048      // edges per k_bin block

__device__ __forceinline__ float lo2f(unsigned u) { return __uint_as_float(u << 16); }
__device__ __forceinline__ float hi2f(unsigned u) { return __uint_as_float(u & 0xFFFF0000u); }
__device__ __forceinline__ unsigned cvt_pk_bf16(float lo, float hi) {
  unsigned r;
  asm("v_cvt_pk_bf16_f32 %0, %1, %2" : "=v"(r) : "v"(lo), "v"(hi));
  return r;
}

__device__ __forceinline__ int wave_scan_incl(int v, int lane) {
#pragma unroll
  for (int off = 1; off < 64; off <<= 1) {
    int t = __shfl_up(v, off, 64);
    if (lane >= off) v += t;
  }
  return v;
}

// init bucket cursors + zero the dummy row n of z0/z1/z2
__global__ void k_init(int* __restrict__ bcursor, int nbkt,
                       unsigned* __restrict__ z0, unsigned* __restrict__ z1,
                       unsigned* __restrict__ z2, int n) {
  int i = blockIdx.x * blockDim.x + threadIdx.x;
  if (i < nbkt) bcursor[i] = i * BKT_CAP;
  if (blockIdx.x == 0 && threadIdx.x < 32) {     // row = 64 bf16 = 32 uints
    size_t o = (size_t)n * 32 + threadIdx.x;
    z0[o] = 0u; z1[o] = 0u; z2[o] = 0u;
  }
}

// radix partition by target bucket; LDS-aggregated so global atomics are
// one per (block, bin) and record writes are grouped per bin.
__global__ __launch_bounds__(256)
void k_bin(const int* __restrict__ row, const int* __restrict__ col,
           int* __restrict__ bcursor, int* __restrict__ tmp, int E, int nbkt) {
  __shared__ int h[1024];                 // nbkt <= 1024
  int e0 = blockIdx.x * EPB;
  int e1 = min(e0 + EPB, E);
  for (int i = threadIdx.x; i < nbkt; i += 256) h[i] = 0;
  __syncthreads();
  for (int e = e0 + threadIdx.x; e < e1; e += 256)
    atomicAdd(&h[col[e] >> BKT_SHIFT], 1);
  __syncthreads();
  for (int i = threadIdx.x; i < nbkt; i += 256) {
    int c = h[i];
    h[i] = c ? atomicAdd(&bcursor[i], c) : 0;   // reserve range, h -> base
  }
  __syncthreads();
  for (int e = e0 + threadIdx.x; e < e1; e += 256) {
    int c = col[e], r = row[e];
    int p = atomicAdd(&h[c >> BKT_SHIFT], 1);
    tmp[p] = r | ((c & (BKT_NODES - 1)) << 20);
  }
}

// per-bucket counting sort -> padded per-node CSR; deg stats; z0 = bf16(dis*emb)
__global__ __launch_bounds__(256)
void k_sort(const int* __restrict__ bcursor, const int* __restrict__ tmp,
            int* __restrict__ srcs, int* __restrict__ obeg, int* __restrict__ oend,
            float* __restrict__ invdeg, float* __restrict__ sdeg,
            const float* __restrict__ emb, unsigned short* __restrict__ z0, int n) {
  __shared__ int hist[BKT_NODES];
  __shared__ int excl[BKT_NODES];
  __shared__ int cur[BKT_NODES];
  __shared__ float sdis[BKT_NODES];
  int b = blockIdx.x;
  int base = b * BKT_CAP;
  int cnt = bcursor[b] - base;
  if (threadIdx.x < BKT_NODES) hist[threadIdx.x] = 0;
  __syncthreads();
  for (int q = threadIdx.x; q < cnt; q += 256)
    atomicAdd(&hist[(unsigned)tmp[base + q] >> 20], 1);
  __syncthreads();
  if (threadIdx.x < 64) {     // scan PADDED lengths; lane l owns bins 2l, 2l+1
    int l = threadIdx.x;
    int h0 = hist[2 * l], h1 = hist[2 * l + 1];
    int p0 = (h0 + 3) & ~3, p1 = (h1 + 3) & ~3;
    int v = p0 + p1;
    int incl = wave_scan_incl(v, l);
    int ex = incl - v;
    excl[2 * l] = ex;      excl[2 * l + 1] = ex + p0;
    cur[2 * l] = ex;       cur[2 * l + 1] = ex + p0;
  }
  __syncthreads();
  int node0 = b << BKT_SHIFT;
  if (threadIdx.x < BKT_NODES) {
    int node = node0 + threadIdx.x;
    if (node < n) {
      int d = hist[threadIdx.x];
      int dpad = (d + 3) & ~3;
      int bg = base + excl[threadIdx.x];
      obeg[node] = bg;
      oend[node] = bg + dpad;                 // padded end for the walk
      float fd = (float)d;
      invdeg[node] = d ? 1.0f / fd : 0.0f;
      sdeg[node] = sqrtf(fd);
      sdis[threadIdx.x] = d ? rsqrtf(fd) : 0.0f;
      for (int p = d; p < dpad; ++p) srcs[bg + p] = n;   // dummy -> zero row
    } else {
      sdis[threadIdx.x] = 0.0f;
    }
  }
  __syncthreads();
  for (int q = threadIdx.x; q < cnt; q += 256) {
    int rec = tmp[base + q];
    int lc = (unsigned)rec >> 20;
    int p = atomicAdd(&cur[lc], 1);
    srcs[base + p] = rec & 0xFFFFF;
  }
  int nloc = min(BKT_NODES, n - node0);
  for (int t = threadIdx.x; t < nloc * 8; t += 256) {
    int rr = t >> 3, q = t & 7;
    float ds = sdis[rr];
    float4 v0 = reinterpret_cast<const float4*>(emb)[(size_t)(node0 + rr) * 16 + 2 * q];
    float4 v1 = reinterpret_cast<const float4*>(emb)[(size_t)(node0 + rr) * 16 + 2 * q + 1];
    uint4 o;
    o.x = cvt_pk_bf16(v0.x * ds, v0.y * ds);
    o.y = cvt_pk_bf16(v0.z * ds, v0.w * ds);
    o.z = cvt_pk_bf16(v1.x * ds, v1.y * ds);
    o.w = cvt_pk_bf16(v1.z * ds, v1.w * ds);
    reinterpret_cast<uint4*>(z0)[(size_t)(node0 + rr) * 8 + q] = o;
  }
}

// 8-lane group per node, 8 nodes per wave; lane l covers dims 8l..8l+7 (uint4).
// Guard-free 4-edge unroll over padded CSR; srcs loaded as int4.
template <bool FINAL>
__global__ __launch_bounds__(256)
void k_prop(const int* __restrict__ obeg, const int* __restrict__ oend,
            const int* __restrict__ srcs, const unsigned short* __restrict__ z,
            unsigned short* __restrict__ zout, const float* __restrict__ invdeg,
            const float* __restrict__ emb, const unsigned short* __restrict__ z1,
            const unsigned short* __restrict__ z2, const float* __restrict__ sdeg,
            float* __restrict__ out, int n) {
  int lane = threadIdx.x & 63;
  int wid = (blockIdx.x * blockDim.x + threadIdx.x) >> 6;   // global wave id
  int g = lane >> 3, l = lane & 7;
  int node = wid * 8 + g;
  if (node >= n) return;
  const uint4* zv = reinterpret_cast<const uint4*>(z);      // row = 8 x uint4
  const int4* sv = reinterpret_cast<const int4*>(srcs);

  int kq = obeg[node] >> 2;
  int endq = oend[node] >> 2;

  float s0 = 0.f, s1 = 0.f, s2 = 0.f, s3 = 0.f;
  float s4 = 0.f, s5 = 0.f, s6 = 0.f, s7 = 0.f;

  int4 sq = make_int4(0, 0, 0, 0);
  if (kq < endq) sq = sv[kq];
  while (kq < endq) {
    uint4 a = zv[(size_t)sq.x * 8 + l];
    uint4 b = zv[(size_t)sq.y * 8 + l];
    uint4 c = zv[(size_t)sq.z * 8 + l];
    uint4 d = zv[(size_t)sq.w * 8 + l];
    ++kq;
    sq = sv[(kq < endq) ? kq : (kq - 1)];
    s0 += lo2f(a.x); s1 += hi2f(a.x); s2 += lo2f(a.y); s3 += hi2f(a.y);
    s4 += lo2f(a.z); s5 += hi2f(a.z); s6 += lo2f(a.w); s7 += hi2f(a.w);
    s0 += lo2f(b.x); s1 += hi2f(b.x); s2 += lo2f(b.y); s3 += hi2f(b.y);
    s4 += lo2f(b.z); s5 += hi2f(b.z); s6 += lo2f(b.w); s7 += hi2f(b.w);
    s0 += lo2f(c.x); s1 += hi2f(c.x); s2 += lo2f(c.y); s3 += hi2f(c.y);
    s4 += lo2f(c.z); s5 += hi2f(c.z); s6 += lo2f(c.w); s7 += hi2f(c.w);
    s0 += lo2f(d.x); s1 += hi2f(d.x); s2 += lo2f(d.y); s3 += hi2f(d.y);
    s4 += lo2f(d.z); s5 += hi2f(d.z); s6 += lo2f(d.w); s7 += hi2f(d.w);
  }

  float idg = invdeg[node];
  size_t gi = (size_t)node * 8 + l;
  if (!FINAL) {
    uint4 o;
    o.x = cvt_pk_bf16(s0 * idg, s1 * idg);
    o.y = cvt_pk_bf16(s2 * idg, s3 * idg);
    o.z = cvt_pk_bf16(s4 * idg, s5 * idg);
    o.w = cvt_pk_bf16(s6 * idg, s7 * idg);
    reinterpret_cast<uint4*>(zout)[gi] = o;
  } else {
    float sd = sdeg[node];
    float c = sd * idg;
    uint4 a1 = reinterpret_cast<const uint4*>(z1)[gi];
    uint4 a2 = reinterpret_cast<const uint4*>(z2)[gi];
    float4 e0 = reinterpret_cast<const float4*>(emb)[(size_t)node * 16 + 2 * l];
    float4 e1 = reinterpret_cast<const float4*>(emb)[(size_t)node * 16 + 2 * l + 1];
    float4 o0, o1;
    o0.x = 0.25f * (e0.x + sd * (lo2f(a1.x) + lo2f(a2.x)) + c * s0);
    o0.y = 0.25f * (e0.y + sd * (hi2f(a1.x) + hi2f(a2.x)) + c * s1);
    o0.z = 0.25f * (e0.z + sd * (lo2f(a1.y) + lo2f(a2.y)) + c * s2);
    o0.w = 0.25f * (e0.w + sd * (hi2f(a1.y) + hi2f(a2.y)) + c * s3);
    o1.x = 0.25f * (e1.x + sd * (lo2f(a1.z) + lo2f(a2.z)) + c * s4);
    o1.y = 0.25f * (e1.y + sd * (hi2f(a1.z) + hi2f(a2.z)) + c * s5);
    o1.z = 0.25f * (e1.w + sd * (lo2f(a1.w) + lo2f(a2.w)) + c * s6);
    o1.w = 0.25f * (e1.w + sd * (hi2f(a1.w) + hi2f(a2.w)) + c * s7);
    // fix typo above: o1.z must use e1.z
    o1.z = 0.25f * (e1.z + sd * (lo2f(a1.w) + lo2f(a2.w)) + c * s6);
    reinterpret_cast<float4*>(out)[(size_t)node * 16 + 2 * l] = o0;
    reinterpret_cast<float4*>(out)[(size_t)node * 16 + 2 * l + 1] = o1;
  }
}

extern "C" void kernel_launch(void* const* d_in, const int* in_sizes, int n_in,
                              void* d_out, int out_size, void* d_ws, size_t ws_size,
                              hipStream_t stream) {
  const int* edge = (const int*)d_in[0];
  const float* emb = (const float*)d_in[1];
  float* out = (float*)d_out;

  const int E = in_sizes[0] / 2;
  const int n = in_sizes[1] / 64;
  const int* row = edge;        // sources j
  const int* col = edge + E;    // targets i
  const int NBKT = (n + BKT_NODES - 1) / BKT_NODES;   // 782

  char* ws = (char*)d_ws;
  size_t off = 0;
  auto alloc = [&](size_t bytes) -> void* {
    void* p = ws + off;
    off += (bytes + 255) & ~(size_t)255;
    return p;
  };
  int*   bcursor = (int*)  alloc((size_t)NBKT * 4);
  int*   tmp     = (int*)  alloc((size_t)NBKT * BKT_CAP * 4);   // ~8 MB
  int*   srcs    = (int*)  alloc((size_t)NBKT * BKT_CAP * 4);   // ~8 MB
  int*   obeg    = (int*)  alloc((size_t)n * 4);
  int*   oend    = (int*)  alloc((size_t)n * 4);
  float* invdeg  = (float*)alloc((size_t)n * 4);
  float* sdeg    = (float*)alloc((size_t)n * 4);
  unsigned short* z0 = (unsigned short*)alloc((size_t)(n + 1) * 64 * 2);
  unsigned short* z1 = (unsigned short*)alloc((size_t)(n + 1) * 64 * 2);
  unsigned short* z2 = (unsigned short*)alloc((size_t)(n + 1) * 64 * 2);
  (void)ws_size; (void)n_in; (void)out_size;

  const int NBB = (E + EPB - 1) / EPB;
  k_init<<<(NBKT + 255) / 256, 256, 0, stream>>>(bcursor, NBKT,
      (unsigned*)z0, (unsigned*)z1, (unsigned*)z2, n);
  k_bin<<<NBB, 256, 0, stream>>>(row, col, bcursor, tmp, E, NBKT);
  k_sort<<<NBKT, 256, 0, stream>>>(bcursor, tmp, srcs, obeg, oend,
                                   invdeg, sdeg, emb, z0, n);

  // 8 nodes per wave, 4 waves per block = 32 nodes/block
  const int pg = (n + 31) / 32;
  k_prop<false><<<pg, 256, 0, stream>>>(obeg, oend, srcs, z0, z1, invdeg,
                                        nullptr, nullptr, nullptr, nullptr, nullptr, n);
  k_prop<false><<<pg, 256, 0, stream>>>(obeg, oend, srcs, z1, z2, invdeg,
                                        nullptr, nullptr, nullptr, nullptr, nullptr, n);
  k_prop<true ><<<pg, 256, 0, stream>>>(obeg, oend, srcs, z2, nullptr, invdeg,
                                        emb, z1, z2, sdeg, out, n);
}